// Round 1
// baseline (319.012 us; speedup 1.0000x reference)
//
#include <hip/hip_runtime.h>
#include <hip/hip_bf16.h>
#include <cstdint>

// MultiHeadAttention: out = ( softmax(causal((X Wq^T)(X Wk^T)^T / 8)) (X Wv^T) ) Wo^T
// B=2, S=2048, D_MODEL=1024, H=16, D_HEAD=64. All MFMA in bf16, accum fp32.
//
// Workspace layout (needs 72 MB):
//  [0,8M)    Qb   bf16 [4096][1024]
//  [8,16M)   Kb   bf16 [4096][1024]
//  [16,24M)  Vb   bf16 [4096][1024]
//  [24,32M)  Vt   bf16 [1024][4096]  (V transposed for PV B-fragments)
//  [32,40M)  Ctx  bf16 [4096][1024]
//  [40,64M)  Xq/Xk/Xv bf16 inputs
//  [64,72M)  Wq/Wk/Wv/Wo bf16 weights

typedef unsigned short u16;
typedef u16 u16x4 __attribute__((ext_vector_type(4)));
typedef u16 u16x8 __attribute__((ext_vector_type(8)));
typedef __bf16 bf16x8 __attribute__((ext_vector_type(8)));
typedef float f32x4 __attribute__((ext_vector_type(4)));

#define S_LEN 2048
#define DM 1024
#define NH 16
#define DH 64
#define BATCH 2
#define MTOT (BATCH*S_LEN)   // 4096

__device__ __forceinline__ u16 f2bf(float f) {
  union { float f; unsigned u; } v; v.f = f;
  unsigned r = v.u + 0x7FFFu + ((v.u >> 16) & 1u);   // RNE
  return (u16)(r >> 16);
}

__device__ __forceinline__ f32x4 mfma16(u16x8 a, u16x8 b, f32x4 c) {
  return __builtin_amdgcn_mfma_f32_16x16x32_bf16(
      __builtin_bit_cast(bf16x8, a), __builtin_bit_cast(bf16x8, b), c, 0, 0, 0);
}

// ---------------------------------------------------------------- fp32->bf16
__global__ __launch_bounds__(256) void cvt_kernel(
    const float* __restrict__ s0, const float* __restrict__ s1,
    const float* __restrict__ s2, const float* __restrict__ s3,
    const float* __restrict__ s4, const float* __restrict__ s5,
    const float* __restrict__ s6,
    u16* __restrict__ d0, u16* __restrict__ d1, u16* __restrict__ d2,
    u16* __restrict__ d3, u16* __restrict__ d4, u16* __restrict__ d5,
    u16* __restrict__ d6) {
  const int y = blockIdx.y;
  const float* s; u16* d; int n;
  switch (y) {
    case 0: s = s0; d = d0; n = MTOT*DM; break;
    case 1: s = s1; d = d1; n = MTOT*DM; break;
    case 2: s = s2; d = d2; n = MTOT*DM; break;
    case 3: s = s3; d = d3; n = DM*DM;   break;
    case 4: s = s4; d = d4; n = DM*DM;   break;
    case 5: s = s5; d = d5; n = DM*DM;   break;
    default: s = s6; d = d6; n = DM*DM;  break;
  }
  int i = (blockIdx.x * 256 + threadIdx.x) * 4;
  if (i >= n) return;
  f32x4 v = *(const f32x4*)&s[i];
  u16x4 o;
  o[0] = f2bf(v[0]); o[1] = f2bf(v[1]); o[2] = f2bf(v[2]); o[3] = f2bf(v[3]);
  *(u16x4*)&d[i] = o;
}

// ---------------------------------------------------------------- GEMM C=A*B^T
// A: [M][K] bf16 row-major, Bw: [N][K] bf16 row-major (torch Linear weight).
// 128x128 tile, BK=32, 4 waves (2x2), each wave 64x64 via 4x4 16x16x32 MFMA.
#define BM 128
#define BN 128
#define BKK 32
#define LDT 40   // padded LDS row (u16 units): 32 + 8 pad -> 80B stride, conflict-free-ish

template<bool F32OUT>
__device__ __forceinline__ void gemm_core(const u16* __restrict__ A,
                                          const u16* __restrict__ Bw,
                                          void* __restrict__ Cv,
                                          int N, int K) {
  __shared__ u16 As[BM * LDT];
  __shared__ u16 Bs[BN * LDT];
  const int tid  = threadIdx.x;
  const int lane = tid & 63, w = tid >> 6;
  const int g = lane >> 4, r16 = lane & 15;
  const int wm = w >> 1, wn = w & 1;
  const int rowBase = blockIdx.y * BM;
  const int colBase = blockIdx.x * BN;
  f32x4 acc[4][4] = {};
  const int srow0 = tid >> 2;          // staging: chunk c = tid + 256*i
  const int kc0   = (tid & 3) * 8;
  for (int k0 = 0; k0 < K; k0 += BKK) {
    __syncthreads();
#pragma unroll
    for (int i = 0; i < 2; i++) {
      int row = srow0 + i * 64;
      u16x8 va = *(const u16x8*)&A [(rowBase + row) * K + k0 + kc0];
      *(u16x8*)&As[row * LDT + kc0] = va;
      u16x8 vb = *(const u16x8*)&Bw[(colBase + row) * K + k0 + kc0];
      *(u16x8*)&Bs[row * LDT + kc0] = vb;
    }
    __syncthreads();
    u16x8 af[4], bfv[4];
#pragma unroll
    for (int i = 0; i < 4; i++) af[i]  = *(const u16x8*)&As[(wm*64 + i*16 + r16) * LDT + g*8];
#pragma unroll
    for (int j = 0; j < 4; j++) bfv[j] = *(const u16x8*)&Bs[(wn*64 + j*16 + r16) * LDT + g*8];
#pragma unroll
    for (int i = 0; i < 4; i++)
#pragma unroll
      for (int j = 0; j < 4; j++) acc[i][j] = mfma16(af[i], bfv[j], acc[i][j]);
  }
  // epilogue: C/D layout col = lane&15, row = 4*(lane>>4)+reg  [HW-verified]
#pragma unroll
  for (int i = 0; i < 4; i++) {
#pragma unroll
    for (int j = 0; j < 4; j++) {
      int row = rowBase + wm*64 + i*16 + 4*g;
      int col = colBase + wn*64 + j*16 + r16;
#pragma unroll
      for (int r = 0; r < 4; r++) {
        if (F32OUT) ((float*)Cv)[(row + r) * N + col] = acc[i][j][r];
        else        ((u16*)Cv)  [(row + r) * N + col] = f2bf(acc[i][j][r]);
      }
    }
  }
}

__global__ __launch_bounds__(256) void qkv_proj_kernel(
    const u16* __restrict__ Xq, const u16* __restrict__ Xk, const u16* __restrict__ Xv,
    const u16* __restrict__ Wq, const u16* __restrict__ Wk, const u16* __restrict__ Wv,
    u16* __restrict__ Qb, u16* __restrict__ Kb, u16* __restrict__ Vb) {
  const int z = blockIdx.z;
  const u16* X = (z == 0) ? Xq : (z == 1) ? Xk : Xv;
  const u16* W = (z == 0) ? Wq : (z == 1) ? Wk : Wv;
  u16*       O = (z == 0) ? Qb : (z == 1) ? Kb : Vb;
  gemm_core<false>(X, W, O, DM, DM);
}

__global__ __launch_bounds__(256) void out_proj_kernel(
    const u16* __restrict__ Ctx, const u16* __restrict__ Wo, float* __restrict__ Out) {
  gemm_core<true>(Ctx, Wo, Out, DM, DM);
}

// ---------------------------------------------------------------- V transpose
// Vb [4096][1024] -> Vt [1024][4096]
__global__ __launch_bounds__(256) void transpose_bf16(const u16* __restrict__ in,
                                                      u16* __restrict__ out) {
  __shared__ u16 tile[64][68];
  const int bx = blockIdx.x * 64;   // col base in 'in' (0..1023)
  const int by = blockIdx.y * 64;   // row base in 'in' (0..4095)
  const int t = threadIdx.x;
  const int tx = t & 15, ty = t >> 4;
#pragma unroll
  for (int i = 0; i < 4; i++) {
    int r = ty + 16 * i;
    u16x4 v = *(const u16x4*)&in[(size_t)(by + r) * DM + bx + 4 * tx];
    *(u16x4*)&tile[r][4 * tx] = v;
  }
  __syncthreads();
#pragma unroll
  for (int i = 0; i < 4; i++) {
    int r = ty + 16 * i;            // out row = bx + r
    u16x4 v;
#pragma unroll
    for (int j = 0; j < 4; j++) v[j] = tile[4 * tx + j][r];
    *(u16x4*)&out[(size_t)(bx + r) * MTOT + by + 4 * tx] = v;
  }
}

// ---------------------------------------------------------------- flash attn
// Grid: (S/64, B*H). 4 waves/block, each wave owns 16 q-rows, kv tiles of 32.
// S-frag (C-layout): q = qbase+4g+r, kv = kv0+16cf+(lane&15).
// P transposed via per-wave LDS to feed PV A-fragments; V read from Vt.
__global__ __launch_bounds__(256) void attn_kernel(const u16* __restrict__ Qb,
                                                   const u16* __restrict__ Kb,
                                                   const u16* __restrict__ Vt,
                                                   u16* __restrict__ Ctx) {
  __shared__ u16 plds[4][2][16 * LDT];
  const int tid = threadIdx.x;
  const int lane = tid & 63, wid = tid >> 6;
  const int g = lane >> 4, r16 = lane & 15;
  const int bh = blockIdx.y, bb = bh >> 4, h = bh & 15;
  const int qbase = blockIdx.x * 64 + wid * 16;
  const int qrow = bb * S_LEN + qbase;

  u16x8 qf[2];
#pragma unroll
  for (int f = 0; f < 2; f++)
    qf[f] = *(const u16x8*)&Qb[(qrow + r16) * DM + h * DH + f * 32 + g * 8];

  f32x4 cacc[4] = {};
  float mrow[4] = {-INFINITY, -INFINITY, -INFINITY, -INFINITY};
  float lrow[4] = {0.f, 0.f, 0.f, 0.f};
  const int tmax = (qbase + 15) >> 5;   // kv0 <= qbase always (qbase mult of 16)

  for (int t = 0; t <= tmax; t++) {
    const int kv0 = t * 32;
    f32x4 s[2];
#pragma unroll
    for (int cf = 0; cf < 2; cf++) {
      const u16* kp = &Kb[(bb * S_LEN + kv0 + cf * 16 + r16) * DM + h * DH + g * 8];
      u16x8 kf0 = *(const u16x8*)kp;
      u16x8 kf1 = *(const u16x8*)(kp + 32);
      f32x4 z = {0.f, 0.f, 0.f, 0.f};
      s[cf] = mfma16(qf[1], kf1, mfma16(qf[0], kf0, z));
    }
#pragma unroll
    for (int cf = 0; cf < 2; cf++)
#pragma unroll
      for (int r = 0; r < 4; r++) s[cf][r] *= 0.125f;   // 1/sqrt(64)

    if (kv0 + 31 > qbase) {   // boundary tile: mask kv > q
#pragma unroll
      for (int cf = 0; cf < 2; cf++)
#pragma unroll
        for (int r = 0; r < 4; r++) {
          int kv = kv0 + cf * 16 + r16;
          int qq = qbase + 4 * g + r;
          if (kv > qq) s[cf][r] = -1e30f;
        }
    }

    float rowm[4], alpha[4], ps[4];
#pragma unroll
    for (int r = 0; r < 4; r++) rowm[r] = fmaxf(s[0][r], s[1][r]);
#pragma unroll
    for (int mk = 1; mk < 16; mk <<= 1)
#pragma unroll
      for (int r = 0; r < 4; r++) rowm[r] = fmaxf(rowm[r], __shfl_xor(rowm[r], mk, 64));
#pragma unroll
    for (int r = 0; r < 4; r++) {
      float mn = fmaxf(mrow[r], rowm[r]);
      alpha[r] = __expf(mrow[r] - mn);
      mrow[r] = mn;
    }
#pragma unroll
    for (int cf = 0; cf < 2; cf++)
#pragma unroll
      for (int r = 0; r < 4; r++) s[cf][r] = __expf(s[cf][r] - mrow[r]);
#pragma unroll
    for (int r = 0; r < 4; r++) ps[r] = s[0][r] + s[1][r];
#pragma unroll
    for (int mk = 1; mk < 16; mk <<= 1)
#pragma unroll
      for (int r = 0; r < 4; r++) ps[r] += __shfl_xor(ps[r], mk, 64);
#pragma unroll
    for (int r = 0; r < 4; r++) lrow[r] = lrow[r] * alpha[r] + ps[r];

    // P (16q x 32kv) -> per-wave LDS (transpose C-layout -> A-layout)
    u16* P = &plds[wid][t & 1][0];
#pragma unroll
    for (int r = 0; r < 4; r++) {
      P[(4 * g + r) * LDT + r16]      = f2bf(s[0][r]);
      P[(4 * g + r) * LDT + 16 + r16] = f2bf(s[1][r]);
    }
    asm volatile("s_waitcnt lgkmcnt(0)" ::: "memory");
    u16x8 pa = *(const u16x8*)&P[r16 * LDT + g * 8];

#pragma unroll
    for (int dq = 0; dq < 4; dq++) {
      u16x8 vf = *(const u16x8*)&Vt[(h * DH + dq * 16 + r16) * MTOT + bb * S_LEN + kv0 + g * 8];
#pragma unroll
      for (int r = 0; r < 4; r++) cacc[dq][r] *= alpha[r];
      cacc[dq] = mfma16(pa, vf, cacc[dq]);
    }
  }

  float lr[4];
#pragma unroll
  for (int r = 0; r < 4; r++) lr[r] = 1.f / lrow[r];
#pragma unroll
  for (int dq = 0; dq < 4; dq++)
#pragma unroll
    for (int r = 0; r < 4; r++)
      Ctx[(qrow + 4 * g + r) * DM + h * DH + dq * 16 + r16] = f2bf(cacc[dq][r] * lr[r]);
}

// ---------------------------------------------------------------- launch
extern "C" void kernel_launch(void* const* d_in, const int* in_sizes, int n_in,
                              void* d_out, int out_size, void* d_ws, size_t ws_size,
                              hipStream_t stream) {
  const float* q_in = (const float*)d_in[0];
  const float* k_in = (const float*)d_in[1];
  const float* v_in = (const float*)d_in[2];
  // d_in[3] = causal mask, unused (causality implemented structurally)
  const float* wq = (const float*)d_in[4];
  const float* wk = (const float*)d_in[5];
  const float* wv = (const float*)d_in[6];
  const float* wo = (const float*)d_in[7];

  char* ws = (char*)d_ws;
  const size_t MB = 1024ull * 1024ull;
  u16* Qb  = (u16*)(ws + 0  * MB);
  u16* Kb  = (u16*)(ws + 8  * MB);
  u16* Vb  = (u16*)(ws + 16 * MB);
  u16* Vt  = (u16*)(ws + 24 * MB);
  u16* Ctx = (u16*)(ws + 32 * MB);
  u16* Xq  = (u16*)(ws + 40 * MB);
  u16* Xk  = (u16*)(ws + 48 * MB);
  u16* Xv  = (u16*)(ws + 56 * MB);
  u16* Wqb = (u16*)(ws + 64 * MB);
  u16* Wkb = (u16*)(ws + 66 * MB);
  u16* Wvb = (u16*)(ws + 68 * MB);
  u16* Wob = (u16*)(ws + 70 * MB);

  cvt_kernel<<<dim3(4096, 7, 1), 256, 0, stream>>>(
      q_in, k_in, v_in, wq, wk, wv, wo, Xq, Xk, Xv, Wqb, Wkb, Wvb, Wob);
  qkv_proj_kernel<<<dim3(DM / BN, MTOT / BM, 3), 256, 0, stream>>>(
      Xq, Xk, Xv, Wqb, Wkb, Wvb, Qb, Kb, Vb);
  transpose_bf16<<<dim3(DM / 64, MTOT / 64), 256, 0, stream>>>(Vb, Vt);
  attn_kernel<<<dim3(S_LEN / 64, BATCH * NH), 256, 0, stream>>>(Qb, Kb, Vt, Ctx);
  out_proj_kernel<<<dim3(DM / BN, MTOT / BM), 256, 0, stream>>>(Ctx, Wob, (float*)d_out);
}

// Round 2
// 219.795 us; speedup vs baseline: 1.4514x; 1.4514x over previous
//
#include <hip/hip_runtime.h>
#include <hip/hip_bf16.h>
#include <cstdint>

// MultiHeadAttention: out = ( softmax(causal((X Wq^T)(X Wk^T)^T / 8)) (X Wv^T) ) Wo^T
// B=2, S=2048, D_MODEL=1024, H=16, D_HEAD=64. All MFMA bf16, accum fp32.
//
// Workspace layout (64 MB):
//  [0,8M)    Qp  bf16 [16][4096][64]  per-head packed, pre-scaled by 1/8
//  [8,16M)   Kp  bf16 [16][4096][64]  per-head packed
//  [16,24M)  Vt  bf16 [1024][4096]    V transposed (row = h*64+d, col = token)
//  [24,32M)  Ctx bf16 [4096][1024]
//  [32,56M)  Xq/Xk/Xv bf16 inputs
//  [56,64M)  Wq/Wk/Wv/Wo bf16 weights

typedef unsigned short u16;
typedef u16 u16x4 __attribute__((ext_vector_type(4)));
typedef u16 u16x8 __attribute__((ext_vector_type(8)));
typedef unsigned u32x4 __attribute__((ext_vector_type(4)));
typedef __bf16 bf16x8 __attribute__((ext_vector_type(8)));
typedef float f32x4 __attribute__((ext_vector_type(4)));
typedef float f32x16 __attribute__((ext_vector_type(16)));

#define S_LEN 2048
#define DM 1024
#define NH 16
#define DH 64
#define BATCH 2
#define MTOT (BATCH*S_LEN)   // 4096

__device__ __forceinline__ u16 f2bf(float f) {
  union { float f; unsigned u; } v; v.f = f;
  unsigned r = v.u + 0x7FFFu + ((v.u >> 16) & 1u);   // RNE
  return (u16)(r >> 16);
}

__device__ __forceinline__ f32x4 mfma16(u16x8 a, u16x8 b, f32x4 c) {
  return __builtin_amdgcn_mfma_f32_16x16x32_bf16(
      __builtin_bit_cast(bf16x8, a), __builtin_bit_cast(bf16x8, b), c, 0, 0, 0);
}
__device__ __forceinline__ f32x16 mfma32(u16x8 a, u16x8 b, f32x16 c) {
  return __builtin_amdgcn_mfma_f32_32x32x16_bf16(
      __builtin_bit_cast(bf16x8, a), __builtin_bit_cast(bf16x8, b), c, 0, 0, 0);
}
__device__ __forceinline__ unsigned cvtpk_bf16(float lo, float hi) {
  unsigned r;
  asm("v_cvt_pk_bf16_f32 %0, %1, %2" : "=v"(r) : "v"(lo), "v"(hi));
  return r;
}
__device__ __forceinline__ void permswap(unsigned &a, unsigned &b) {
  asm volatile("v_permlane32_swap_b32 %0, %1" : "+v"(a), "+v"(b));
}

// ---------------------------------------------------------------- fp32->bf16
__global__ __launch_bounds__(256) void cvt_kernel(
    const float* __restrict__ s0, const float* __restrict__ s1,
    const float* __restrict__ s2, const float* __restrict__ s3,
    const float* __restrict__ s4, const float* __restrict__ s5,
    const float* __restrict__ s6,
    u16* __restrict__ d0, u16* __restrict__ d1, u16* __restrict__ d2,
    u16* __restrict__ d3, u16* __restrict__ d4, u16* __restrict__ d5,
    u16* __restrict__ d6) {
  const int y = blockIdx.y;
  const float* s; u16* d; int n;
  switch (y) {
    case 0: s = s0; d = d0; n = MTOT*DM; break;
    case 1: s = s1; d = d1; n = MTOT*DM; break;
    case 2: s = s2; d = d2; n = MTOT*DM; break;
    case 3: s = s3; d = d3; n = DM*DM;   break;
    case 4: s = s4; d = d4; n = DM*DM;   break;
    case 5: s = s5; d = d5; n = DM*DM;   break;
    default: s = s6; d = d6; n = DM*DM;  break;
  }
  int i = (blockIdx.x * 256 + threadIdx.x) * 4;
  if (i >= n) return;
  f32x4 v = *(const f32x4*)&s[i];
  u16x4 o;
  o[0] = f2bf(v[0]); o[1] = f2bf(v[1]); o[2] = f2bf(v[2]); o[3] = f2bf(v[3]);
  *(u16x4*)&d[i] = o;
}

// ---------------------------------------------------------------- GEMM C=A*B^T
// A: [M][K] bf16 row-major, Bw: [N][K] bf16 row-major. 128x128 tile, BK=32,
// 4 waves (2x2), each 64x64 via 4x4 16x16x32 MFMA. N = 1024 fixed.
// MODE 0: bf16 out, per-head packed [16][4096][64], scaled.
// MODE 1: bf16 out, transposed [1024][4096].
// MODE 2: f32 out, plain [M][1024].
#define BM 128
#define BN 128
#define BKK 32
#define LDT 40

template<int MODE>
__device__ __forceinline__ void gemm_core(const u16* __restrict__ A,
                                          const u16* __restrict__ Bw,
                                          void* __restrict__ Cv,
                                          int K, float scale) {
  __shared__ u16 As[BM * LDT];
  __shared__ u16 Bs[BN * LDT];
  const int tid  = threadIdx.x;
  const int lane = tid & 63, w = tid >> 6;
  const int g = lane >> 4, r16 = lane & 15;
  const int wm = w >> 1, wn = w & 1;
  const int rowBase = blockIdx.y * BM;
  const int colBase = blockIdx.x * BN;
  f32x4 acc[4][4] = {};
  const int srow0 = tid >> 2;
  const int kc0   = (tid & 3) * 8;
  for (int k0 = 0; k0 < K; k0 += BKK) {
    __syncthreads();
#pragma unroll
    for (int i = 0; i < 2; i++) {
      int row = srow0 + i * 64;
      u16x8 va = *(const u16x8*)&A [(rowBase + row) * K + k0 + kc0];
      *(u16x8*)&As[row * LDT + kc0] = va;
      u16x8 vb = *(const u16x8*)&Bw[(colBase + row) * K + k0 + kc0];
      *(u16x8*)&Bs[row * LDT + kc0] = vb;
    }
    __syncthreads();
    u16x8 af[4], bfv[4];
#pragma unroll
    for (int i = 0; i < 4; i++) af[i]  = *(const u16x8*)&As[(wm*64 + i*16 + r16) * LDT + g*8];
#pragma unroll
    for (int j = 0; j < 4; j++) bfv[j] = *(const u16x8*)&Bs[(wn*64 + j*16 + r16) * LDT + g*8];
#pragma unroll
    for (int i = 0; i < 4; i++)
#pragma unroll
      for (int j = 0; j < 4; j++) acc[i][j] = mfma16(af[i], bfv[j], acc[i][j]);
  }
  // C/D layout: col = lane&15, row = 4*(lane>>4)+reg
#pragma unroll
  for (int i = 0; i < 4; i++) {
#pragma unroll
    for (int j = 0; j < 4; j++) {
      int row = rowBase + wm*64 + i*16 + 4*g;
      int col = colBase + wn*64 + j*16 + r16;
      if (MODE == 0) {
        u16* O = (u16*)Cv;
        int head = col >> 6, d = col & 63;
#pragma unroll
        for (int r = 0; r < 4; r++)
          O[((size_t)head * MTOT + row + r) * DH + d] = f2bf(acc[i][j][r] * scale);
      } else if (MODE == 1) {
        u16x4 o;
#pragma unroll
        for (int r = 0; r < 4; r++) o[r] = f2bf(acc[i][j][r]);
        *(u16x4*)&((u16*)Cv)[(size_t)col * MTOT + row] = o;
      } else {
#pragma unroll
        for (int r = 0; r < 4; r++)
          ((float*)Cv)[(size_t)(row + r) * DM + col] = acc[i][j][r];
      }
    }
  }
}

__global__ __launch_bounds__(256) void qkv_proj_kernel(
    const u16* __restrict__ Xq, const u16* __restrict__ Xk, const u16* __restrict__ Xv,
    const u16* __restrict__ Wq, const u16* __restrict__ Wk, const u16* __restrict__ Wv,
    u16* __restrict__ Qp, u16* __restrict__ Kp, u16* __restrict__ Vt) {
  const int z = blockIdx.z;
  if (z == 0)      gemm_core<0>(Xq, Wq, Qp, DM, 0.125f);  // Q pre-scaled by 1/sqrt(64)
  else if (z == 1) gemm_core<0>(Xk, Wk, Kp, DM, 1.0f);
  else             gemm_core<1>(Xv, Wv, Vt, DM, 1.0f);
}

__global__ __launch_bounds__(256) void out_proj_kernel(
    const u16* __restrict__ Ctx, const u16* __restrict__ Wo, float* __restrict__ Out) {
  gemm_core<2>(Ctx, Wo, Out, DM, 1.0f);
}

// ---------------------------------------------------------------- flash attn
// Grid (16, 32), 4 waves/block, no LDS, no barriers. Wave owns 32 q-rows.
// Swapped QK^T: S^T[kv][q] = K·Q^T via mfma32(A=K-frag, B=Q-frag); each lane
// owns q-column (lane&31) -> softmax stats lane-local (pair-combine via
// shfl_xor 32). P -> bf16 A-frags in-register: cvt_pk + permlane32_swap.
// PV: ctx[q][d] += P·V with B = V-frag read from Vt (contiguous u16x8).
__global__ __launch_bounds__(256) void attn_kernel(const u16* __restrict__ Qp,
                                                   const u16* __restrict__ Kp,
                                                   const u16* __restrict__ Vt,
                                                   u16* __restrict__ Ctx) {
  const int tid = threadIdx.x;
  const int lane = tid & 63, wid = tid >> 6;
  const int q32 = lane & 31, hi = lane >> 5;
  const int bh = blockIdx.y, bb = bh >> 4, h = bh & 15;
  const int chunk = 15 - blockIdx.x;            // heavy blocks dispatch first
  const int qbase = chunk * 128 + wid * 32;

  const u16* Qbase = Qp + (size_t)(h * MTOT + bb * S_LEN) * DH;
  const u16* Kbase = Kp + (size_t)(h * MTOT + bb * S_LEN) * DH;
  const u16* Vbase = Vt + (size_t)(h * DH) * MTOT + bb * S_LEN;

  u16x8 qf[4];
#pragma unroll
  for (int ds = 0; ds < 4; ds++)
    qf[ds] = *(const u16x8*)&Qbase[(size_t)(qbase + q32) * DH + ds * 16 + hi * 8];

  f32x16 ctx0 = {}, ctx1 = {};
  float m = -3.0e38f, l = 0.f;
  const int ntiles = ((qbase + 31) >> 6) + 1;

  for (int t = 0; t < ntiles; ++t) {
    const int kv0 = t * 64;
    f32x16 s0 = {}, s1 = {};
#pragma unroll
    for (int ds = 0; ds < 4; ds++) {
      u16x8 kf0 = *(const u16x8*)&Kbase[(size_t)(kv0 + q32) * DH + ds * 16 + hi * 8];
      u16x8 kf1 = *(const u16x8*)&Kbase[(size_t)(kv0 + 32 + q32) * DH + ds * 16 + hi * 8];
      s0 = mfma32(kf0, qf[ds], s0);
      s1 = mfma32(kf1, qf[ds], s1);
    }
    if (t == ntiles - 1) {       // only the last tile can cross the diagonal
      const int qg = qbase + q32;
#pragma unroll
      for (int r = 0; r < 16; r++) {
        int kvr = kv0 + (r & 3) + 8 * (r >> 2) + 4 * hi;
        if (kvr > qg)      s0[r] = -1e30f;
        if (kvr + 32 > qg) s1[r] = -1e30f;
      }
    }
    // per-q (lane-local) tile max
    float pmax = s0[0];
#pragma unroll
    for (int r = 1; r < 16; r++) pmax = fmaxf(pmax, s0[r]);
#pragma unroll
    for (int r = 0; r < 16; r++) pmax = fmaxf(pmax, s1[r]);
    pmax = fmaxf(pmax, __shfl_xor(pmax, 32, 64));
    // defer-max: rescale ctx only when max grows by > THR (rare)
    if (__ballot(pmax > m + 8.f)) {
      float mnew = fmaxf(m, pmax);
      float alpha = __expf(m - mnew);
      l *= alpha;
      m = mnew;
#pragma unroll
      for (int r = 0; r < 16; r++) {
        float f = __shfl(alpha, (r & 3) + 8 * (r >> 2) + 4 * hi, 64);
        ctx0[r] *= f; ctx1[r] *= f;
      }
    }
    float psum = 0.f;
#pragma unroll
    for (int r = 0; r < 16; r++) { s0[r] = __expf(s0[r] - m); psum += s0[r]; }
#pragma unroll
    for (int r = 0; r < 16; r++) { s1[r] = __expf(s1[r] - m); psum += s1[r]; }
    psum += __shfl_xor(psum, 32, 64);
    l += psum;

    // P (f32, C-layout) -> 4 bf16 A-fragments, fully in-register (T12)
    u16x8 pa[4];
#pragma unroll
    for (int tt = 0; tt < 2; tt++) {
      unsigned pk[8];
#pragma unroll
      for (int i = 0; i < 8; i++) {
        float a = tt ? s1[2*i] : s0[2*i];
        float b = tt ? s1[2*i+1] : s0[2*i+1];
        pk[i] = cvtpk_bf16(a, b);
      }
      permswap(pk[0], pk[2]); permswap(pk[1], pk[3]);
      permswap(pk[4], pk[6]); permswap(pk[5], pk[7]);
      u32x4 w0 = {pk[0], pk[1], pk[2], pk[3]};
      u32x4 w1 = {pk[4], pk[5], pk[6], pk[7]};
      pa[2*tt]   = __builtin_bit_cast(u16x8, w0);
      pa[2*tt+1] = __builtin_bit_cast(u16x8, w1);
    }
#pragma unroll
    for (int ks = 0; ks < 4; ks++) {
      u16x8 vf0 = *(const u16x8*)&Vbase[(size_t)q32 * MTOT        + kv0 + ks * 16 + hi * 8];
      u16x8 vf1 = *(const u16x8*)&Vbase[(size_t)(32 + q32) * MTOT + kv0 + ks * 16 + hi * 8];
      ctx0 = mfma32(pa[ks], vf0, ctx0);
      ctx1 = mfma32(pa[ks], vf1, ctx1);
    }
  }

  float linv = 1.f / l;
#pragma unroll
  for (int r = 0; r < 16; r++) {
    float f = __shfl(linv, (r & 3) + 8 * (r >> 2) + 4 * hi, 64);
    int qr = (r & 3) + 8 * (r >> 2) + 4 * hi;
    size_t grow = (size_t)(bb * S_LEN + qbase + qr) * DM + h * DH;
    Ctx[grow + q32]      = f2bf(ctx0[r] * f);
    Ctx[grow + 32 + q32] = f2bf(ctx1[r] * f);
  }
}

// ---------------------------------------------------------------- launch
extern "C" void kernel_launch(void* const* d_in, const int* in_sizes, int n_in,
                              void* d_out, int out_size, void* d_ws, size_t ws_size,
                              hipStream_t stream) {
  const float* q_in = (const float*)d_in[0];
  const float* k_in = (const float*)d_in[1];
  const float* v_in = (const float*)d_in[2];
  // d_in[3] = causal mask, unused (causality structural)
  const float* wq = (const float*)d_in[4];
  const float* wk = (const float*)d_in[5];
  const float* wv = (const float*)d_in[6];
  const float* wo = (const float*)d_in[7];

  char* ws = (char*)d_ws;
  const size_t MB = 1024ull * 1024ull;
  u16* Qp  = (u16*)(ws + 0  * MB);
  u16* Kp  = (u16*)(ws + 8  * MB);
  u16* Vt  = (u16*)(ws + 16 * MB);
  u16* Ctx = (u16*)(ws + 24 * MB);
  u16* Xq  = (u16*)(ws + 32 * MB);
  u16* Xk  = (u16*)(ws + 40 * MB);
  u16* Xv  = (u16*)(ws + 48 * MB);
  u16* Wqb = (u16*)(ws + 56 * MB);
  u16* Wkb = (u16*)(ws + 58 * MB);
  u16* Wvb = (u16*)(ws + 60 * MB);
  u16* Wob = (u16*)(ws + 62 * MB);

  cvt_kernel<<<dim3(4096, 7, 1), 256, 0, stream>>>(
      q_in, k_in, v_in, wq, wk, wv, wo, Xq, Xk, Xv, Wqb, Wkb, Wvb, Wob);
  qkv_proj_kernel<<<dim3(DM / BN, MTOT / BM, 3), 256, 0, stream>>>(
      Xq, Xk, Xv, Wqb, Wkb, Wvb, Qp, Kp, Vt);
  attn_kernel<<<dim3(16, BATCH * NH), 256, 0, stream>>>(Qp, Kp, Vt, Ctx);
  out_proj_kernel<<<dim3(DM / BN, MTOT / BM), 256, 0, stream>>>(Ctx, Wob, (float*)d_out);
}

// Round 3
// 170.363 us; speedup vs baseline: 1.8725x; 1.2902x over previous
//
#include <hip/hip_runtime.h>
#include <hip/hip_bf16.h>
#include <cstdint>

// MultiHeadAttention: out = ( softmax(causal((X Wq^T)(X Wk^T)^T / 8)) (X Wv^T) ) Wo^T
// B=2, S=2048, D_MODEL=1024, H=16, D_HEAD=64. All MFMA bf16, accum fp32.
//
// Workspace layout (64 MB):
//  [0,8M)    Qp  bf16 [16][4096][64]  per-head packed, pre-scaled by log2e/8
//  [8,16M)   Kp  bf16 [16][4096][64]  per-head packed
//  [16,24M)  Vt  bf16 [1024][4096]    V transposed (row = h*64+d, col = token)
//  [24,32M)  Ctx bf16 [4096][1024]
//  [32,56M)  Xq/Xk/Xv bf16 inputs
//  [56,64M)  Wq/Wk/Wv/Wo bf16 weights

typedef unsigned short u16;
typedef u16 u16x4 __attribute__((ext_vector_type(4)));
typedef u16 u16x8 __attribute__((ext_vector_type(8)));
typedef unsigned u32x4 __attribute__((ext_vector_type(4)));
typedef __bf16 bf16x8 __attribute__((ext_vector_type(8)));
typedef float f32x4 __attribute__((ext_vector_type(4)));
typedef float f32x16 __attribute__((ext_vector_type(16)));

#define S_LEN 2048
#define DM 1024
#define NH 16
#define DH 64
#define BATCH 2
#define MTOT (BATCH*S_LEN)   // 4096

__device__ __forceinline__ u16 f2bf(float f) {
  union { float f; unsigned u; } v; v.f = f;
  unsigned r = v.u + 0x7FFFu + ((v.u >> 16) & 1u);   // RNE
  return (u16)(r >> 16);
}

__device__ __forceinline__ f32x4 mfma16(u16x8 a, u16x8 b, f32x4 c) {
  return __builtin_amdgcn_mfma_f32_16x16x32_bf16(
      __builtin_bit_cast(bf16x8, a), __builtin_bit_cast(bf16x8, b), c, 0, 0, 0);
}
__device__ __forceinline__ f32x16 mfma32(u16x8 a, u16x8 b, f32x16 c) {
  return __builtin_amdgcn_mfma_f32_32x32x16_bf16(
      __builtin_bit_cast(bf16x8, a), __builtin_bit_cast(bf16x8, b), c, 0, 0, 0);
}
__device__ __forceinline__ unsigned cvtpk_bf16(float lo, float hi) {
  unsigned r;
  asm("v_cvt_pk_bf16_f32 %0, %1, %2" : "=v"(r) : "v"(lo), "v"(hi));
  return r;
}
__device__ __forceinline__ void permswap(unsigned &a, unsigned &b) {
  asm volatile("v_permlane32_swap_b32 %0, %1" : "+v"(a), "+v"(b));
}
// async global -> LDS, 16B per lane; LDS dest = wave-uniform base + lane*16
__device__ __forceinline__ void gload16(const u16* g, u16* l) {
  __builtin_amdgcn_global_load_lds(
      (const __attribute__((address_space(1))) unsigned int*)g,
      (__attribute__((address_space(3))) unsigned int*)l, 16, 0, 0);
}

// ---------------------------------------------------------------- fp32->bf16
__global__ __launch_bounds__(256) void cvt_kernel(
    const float* __restrict__ s0, const float* __restrict__ s1,
    const float* __restrict__ s2, const float* __restrict__ s3,
    const float* __restrict__ s4, const float* __restrict__ s5,
    const float* __restrict__ s6,
    u16* __restrict__ d0, u16* __restrict__ d1, u16* __restrict__ d2,
    u16* __restrict__ d3, u16* __restrict__ d4, u16* __restrict__ d5,
    u16* __restrict__ d6) {
  const int y = blockIdx.y;
  const float* s; u16* d; int n;
  switch (y) {
    case 0: s = s0; d = d0; n = MTOT*DM; break;
    case 1: s = s1; d = d1; n = MTOT*DM; break;
    case 2: s = s2; d = d2; n = MTOT*DM; break;
    case 3: s = s3; d = d3; n = DM*DM;   break;
    case 4: s = s4; d = d4; n = DM*DM;   break;
    case 5: s = s5; d = d5; n = DM*DM;   break;
    default: s = s6; d = d6; n = DM*DM;  break;
  }
  int i = (blockIdx.x * 256 + threadIdx.x) * 4;
  if (i >= n) return;
  f32x4 v = *(const f32x4*)&s[i];
  u16x4 o;
  o[0] = f2bf(v[0]); o[1] = f2bf(v[1]); o[2] = f2bf(v[2]); o[3] = f2bf(v[3]);
  *(u16x4*)&d[i] = o;
}

// ---------------------------------------------------------------- GEMM C=A*B^T
// m97 structure: 128x128 tile, BK=32, 4 waves (2x2), global_load_lds width-16
// staging into LINEAR LDS [128][32], 2 barriers per K-step, 4x4 16x16x32 MFMA.
// MODE 0: bf16 out, per-head packed [16][4096][64], scaled.
// MODE 1: bf16 out, transposed [1024][4096].
// MODE 2: f32 out, plain [M][1024].
#define BM 128
#define BN 128
#define BKK 32

template<int MODE>
__device__ __forceinline__ void gemm_core(const u16* __restrict__ A,
                                          const u16* __restrict__ Bw,
                                          void* __restrict__ Cv,
                                          int K, float scale) {
  __shared__ u16 As[BM * BKK];
  __shared__ u16 Bs[BN * BKK];
  const int tid  = threadIdx.x;
  const int lane = tid & 63, w = tid >> 6;
  const int g = lane >> 4, r16 = lane & 15;
  const int wm = w >> 1, wn = w & 1;
  const int rowBase = blockIdx.y * BM;
  const int colBase = blockIdx.x * BN;
  f32x4 acc[4][4] = {};
  // staging geometry: chunk c = w*2+j covers tile rows [c*16, c*16+16),
  // lane covers row c*16 + lane/4, 16B piece (lane&3). LDS linear.
  const int srow = lane >> 2;
  const int skc  = (lane & 3) * 8;
  const u16* gA[2]; const u16* gB[2]; u16* lA[2]; u16* lB[2];
#pragma unroll
  for (int j = 0; j < 2; j++) {
    const int c = w * 2 + j;
    gA[j] = &A [(size_t)(rowBase + c * 16 + srow) * K + skc];
    gB[j] = &Bw[(size_t)(colBase + c * 16 + srow) * K + skc];
    lA[j] = &As[c * 512];
    lB[j] = &Bs[c * 512];
  }
  for (int k0 = 0; k0 < K; k0 += BKK) {
    __syncthreads();
#pragma unroll
    for (int j = 0; j < 2; j++) {
      gload16(gA[j] + k0, lA[j]);
      gload16(gB[j] + k0, lB[j]);
    }
    __syncthreads();
    u16x8 af[4], bfv[4];
#pragma unroll
    for (int i = 0; i < 4; i++) af[i]  = *(const u16x8*)&As[(wm*64 + i*16 + r16) * BKK + g*8];
#pragma unroll
    for (int j = 0; j < 4; j++) bfv[j] = *(const u16x8*)&Bs[(wn*64 + j*16 + r16) * BKK + g*8];
    __builtin_amdgcn_s_setprio(1);
#pragma unroll
    for (int i = 0; i < 4; i++)
#pragma unroll
      for (int j = 0; j < 4; j++) acc[i][j] = mfma16(af[i], bfv[j], acc[i][j]);
    __builtin_amdgcn_s_setprio(0);
  }
  // C/D layout: col = lane&15, row = 4*(lane>>4)+reg
#pragma unroll
  for (int i = 0; i < 4; i++) {
#pragma unroll
    for (int j = 0; j < 4; j++) {
      int row = rowBase + wm*64 + i*16 + 4*g;
      int col = colBase + wn*64 + j*16 + r16;
      if (MODE == 0) {
        u16* O = (u16*)Cv;
        int head = col >> 6, d = col & 63;
#pragma unroll
        for (int r = 0; r < 4; r++)
          O[((size_t)head * MTOT + row + r) * DH + d] = f2bf(acc[i][j][r] * scale);
      } else if (MODE == 1) {
        u16x4 o;
#pragma unroll
        for (int r = 0; r < 4; r++) o[r] = f2bf(acc[i][j][r]);
        *(u16x4*)&((u16*)Cv)[(size_t)col * MTOT + row] = o;
      } else {
#pragma unroll
        for (int r = 0; r < 4; r++)
          ((float*)Cv)[(size_t)(row + r) * DM + col] = acc[i][j][r];
      }
    }
  }
}

__global__ __launch_bounds__(256) void qkv_proj_kernel(
    const u16* __restrict__ Xq, const u16* __restrict__ Xk, const u16* __restrict__ Xv,
    const u16* __restrict__ Wq, const u16* __restrict__ Wk, const u16* __restrict__ Wv,
    u16* __restrict__ Qp, u16* __restrict__ Kp, u16* __restrict__ Vt) {
  const int z = blockIdx.z;
  // Q pre-scaled by (1/sqrt(64)) * log2(e) -> softmax in exp2 domain
  if (z == 0)      gemm_core<0>(Xq, Wq, Qp, DM, 0.125f * 1.44269504f);
  else if (z == 1) gemm_core<0>(Xk, Wk, Kp, DM, 1.0f);
  else             gemm_core<1>(Xv, Wv, Vt, DM, 1.0f);
}

__global__ __launch_bounds__(256) void out_proj_kernel(
    const u16* __restrict__ Ctx, const u16* __restrict__ Wo, float* __restrict__ Out) {
  gemm_core<2>(Ctx, Wo, Out, DM, 1.0f);
}

// ---------------------------------------------------------------- flash attn
// Grid 512 blocks, 4 waves/block, no LDS/barriers. Wave owns 32 q-rows.
// Swapped QK^T (S^T = K Q^T): lane owns q-column -> lane-local softmax.
// K fragments double-buffered in registers (prefetch t+1 during t);
// V loads issued under the softmax VALU. exp2-domain softmax (log2e folded
// into Q). T12 cvt_pk+permlane32_swap for P->bf16, T13 defer-max, T5 setprio.
// XCD-bijective block remap: each XCD owns 4 (b,h) pairs (2MB K+V in 4MB L2).

#define LOADK(KF, T)                                                           \
  {                                                                            \
    const int kv0_ = (T) * 64;                                                 \
    _Pragma("unroll")                                                          \
    for (int ds = 0; ds < 4; ds++) {                                           \
      KF[2*ds]   = *(const u16x8*)&Kbase[(size_t)(kv0_ + q32) * DH + ds*16 + hi*8];      \
      KF[2*ds+1] = *(const u16x8*)&Kbase[(size_t)(kv0_ + 32 + q32) * DH + ds*16 + hi*8]; \
    }                                                                          \
  }

#define TILE_BODY(KF, T)                                                       \
  {                                                                            \
    const int kv0 = (T) * 64;                                                  \
    f32x16 s0 = {}, s1 = {};                                                   \
    __builtin_amdgcn_s_setprio(1);                                             \
    _Pragma("unroll")                                                          \
    for (int ds = 0; ds < 4; ds++) {                                           \
      s0 = mfma32(KF[2*ds],   qf[ds], s0);                                     \
      s1 = mfma32(KF[2*ds+1], qf[ds], s1);                                     \
    }                                                                          \
    __builtin_amdgcn_s_setprio(0);                                             \
    u16x8 vf[8];                                                               \
    _Pragma("unroll")                                                          \
    for (int ks = 0; ks < 4; ks++) {                                           \
      vf[2*ks]   = *(const u16x8*)&Vbase[(size_t)q32 * MTOT        + kv0 + ks*16 + hi*8]; \
      vf[2*ks+1] = *(const u16x8*)&Vbase[(size_t)(32 + q32) * MTOT + kv0 + ks*16 + hi*8]; \
    }                                                                          \
    if ((T) == ntiles - 1) {                                                   \
      const int qg = qbase + q32;                                              \
      _Pragma("unroll")                                                        \
      for (int r = 0; r < 16; r++) {                                           \
        int kvr = kv0 + (r & 3) + 8 * (r >> 2) + 4 * hi;                       \
        if (kvr > qg)      s0[r] = -1e30f;                                     \
        if (kvr + 32 > qg) s1[r] = -1e30f;                                     \
      }                                                                        \
    }                                                                          \
    float pmax = s0[0];                                                        \
    _Pragma("unroll")                                                          \
    for (int r = 1; r < 16; r++) pmax = fmaxf(pmax, s0[r]);                    \
    _Pragma("unroll")                                                          \
    for (int r = 0; r < 16; r++) pmax = fmaxf(pmax, s1[r]);                    \
    pmax = fmaxf(pmax, __shfl_xor(pmax, 32, 64));                              \
    if (__ballot(pmax > m + 11.5f)) {   /* defer-max, THR = 8/ln2 */           \
      float mnew = fmaxf(m, pmax);                                             \
      float alpha = exp2f(m - mnew);                                           \
      l *= alpha; m = mnew;                                                    \
      _Pragma("unroll")                                                        \
      for (int r = 0; r < 16; r++) {                                           \
        float fsc = __shfl(alpha, (r & 3) + 8 * (r >> 2) + 4 * hi, 64);        \
        ctx0[r] *= fsc; ctx1[r] *= fsc;                                        \
      }                                                                        \
    }                                                                          \
    float psum = 0.f;                                                          \
    _Pragma("unroll")                                                          \
    for (int r = 0; r < 16; r++) { s0[r] = exp2f(s0[r] - m); psum += s0[r]; }  \
    _Pragma("unroll")                                                          \
    for (int r = 0; r < 16; r++) { s1[r] = exp2f(s1[r] - m); psum += s1[r]; }  \
    psum += __shfl_xor(psum, 32, 64);                                          \
    l += psum;                                                                 \
    u16x8 pa[4];                                                               \
    _Pragma("unroll")                                                          \
    for (int tt = 0; tt < 2; tt++) {                                           \
      unsigned pk[8];                                                          \
      _Pragma("unroll")                                                        \
      for (int i = 0; i < 8; i++)                                              \
        pk[i] = cvtpk_bf16(tt ? s1[2*i] : s0[2*i], tt ? s1[2*i+1] : s0[2*i+1]);\
      permswap(pk[0], pk[2]); permswap(pk[1], pk[3]);                          \
      permswap(pk[4], pk[6]); permswap(pk[5], pk[7]);                          \
      u32x4 w0 = {pk[0], pk[1], pk[2], pk[3]};                                 \
      u32x4 w1 = {pk[4], pk[5], pk[6], pk[7]};                                 \
      pa[2*tt]   = __builtin_bit_cast(u16x8, w0);                              \
      pa[2*tt+1] = __builtin_bit_cast(u16x8, w1);                              \
    }                                                                          \
    __builtin_amdgcn_s_setprio(1);                                             \
    _Pragma("unroll")                                                          \
    for (int ks = 0; ks < 4; ks++) {                                           \
      ctx0 = mfma32(pa[ks], vf[2*ks],   ctx0);                                 \
      ctx1 = mfma32(pa[ks], vf[2*ks+1], ctx1);                                 \
    }                                                                          \
    __builtin_amdgcn_s_setprio(0);                                             \
  }

__global__ __launch_bounds__(256, 2) void attn_kernel(const u16* __restrict__ Qp,
                                                      const u16* __restrict__ Kp,
                                                      const u16* __restrict__ Vt,
                                                      u16* __restrict__ Ctx) {
  const int tid = threadIdx.x;
  const int lane = tid & 63, wid = tid >> 6;
  const int q32 = lane & 31, hi = lane >> 5;
  // XCD-bijective remap (assumes XCD = flat % 8): XCD owns bh { xcd*4 .. +3 },
  // heavy chunks dispatched first within each XCD's stream.
  const int flat = blockIdx.x + (int)gridDim.x * blockIdx.y;   // 0..511
  const int xcd = flat & 7, idx = flat >> 3;                   // idx 0..63
  const int bh = xcd * 4 + (idx & 3);
  const int chunk = 15 - (idx >> 2);
  const int bb = bh >> 4, h = bh & 15;
  const int qbase = chunk * 128 + wid * 32;

  const u16* Qbase = Qp + (size_t)(h * MTOT + bb * S_LEN) * DH;
  const u16* Kbase = Kp + (size_t)(h * MTOT + bb * S_LEN) * DH;
  const u16* Vbase = Vt + (size_t)(h * DH) * MTOT + bb * S_LEN;

  u16x8 qf[4];
#pragma unroll
  for (int ds = 0; ds < 4; ds++)
    qf[ds] = *(const u16x8*)&Qbase[(size_t)(qbase + q32) * DH + ds * 16 + hi * 8];

  f32x16 ctx0 = {}, ctx1 = {};
  float m = -3.0e38f, l = 0.f;
  const int ntiles = ((qbase + 31) >> 6) + 1;

  u16x8 kA[8], kB[8];
  LOADK(kA, 0);
  for (int t = 0; t < ntiles; t += 2) {
    if (t + 1 < ntiles) LOADK(kB, t + 1);
    TILE_BODY(kA, t);
    if (t + 1 < ntiles) {
      if (t + 2 < ntiles) LOADK(kA, t + 2);
      TILE_BODY(kB, t + 1);
    }
  }

  float linv = 1.f / l;
#pragma unroll
  for (int r = 0; r < 16; r++) {
    float f = __shfl(linv, (r & 3) + 8 * (r >> 2) + 4 * hi, 64);
    int qr = (r & 3) + 8 * (r >> 2) + 4 * hi;
    size_t grow = (size_t)(bb * S_LEN + qbase + qr) * DM + h * DH;
    Ctx[grow + q32]      = f2bf(ctx0[r] * f);
    Ctx[grow + 32 + q32] = f2bf(ctx1[r] * f);
  }
}

// ---------------------------------------------------------------- launch
extern "C" void kernel_launch(void* const* d_in, const int* in_sizes, int n_in,
                              void* d_out, int out_size, void* d_ws, size_t ws_size,
                              hipStream_t stream) {
  const float* q_in = (const float*)d_in[0];
  const float* k_in = (const float*)d_in[1];
  const float* v_in = (const float*)d_in[2];
  // d_in[3] = causal mask, unused (causality structural)
  const float* wq = (const float*)d_in[4];
  const float* wk = (const float*)d_in[5];
  const float* wv = (const float*)d_in[6];
  const float* wo = (const float*)d_in[7];

  char* ws = (char*)d_ws;
  const size_t MB = 1024ull * 1024ull;
  u16* Qp  = (u16*)(ws + 0  * MB);
  u16* Kp  = (u16*)(ws + 8  * MB);
  u16* Vt  = (u16*)(ws + 16 * MB);
  u16* Ctx = (u16*)(ws + 24 * MB);
  u16* Xq  = (u16*)(ws + 32 * MB);
  u16* Xk  = (u16*)(ws + 40 * MB);
  u16* Xv  = (u16*)(ws + 48 * MB);
  u16* Wqb = (u16*)(ws + 56 * MB);
  u16* Wkb = (u16*)(ws + 58 * MB);
  u16* Wvb = (u16*)(ws + 60 * MB);
  u16* Wob = (u16*)(ws + 62 * MB);

  cvt_kernel<<<dim3(4096, 7, 1), 256, 0, stream>>>(
      q_in, k_in, v_in, wq, wk, wv, wo, Xq, Xk, Xv, Wqb, Wkb, Wvb, Wob);
  qkv_proj_kernel<<<dim3(DM / BN, MTOT / BM, 3), 256, 0, stream>>>(
      Xq, Xk, Xv, Wqb, Wkb, Wvb, Qp, Kp, Vt);
  attn_kernel<<<dim3(16, BATCH * NH), 256, 0, stream>>>(Qp, Kp, Vt, Ctx);
  out_proj_kernel<<<dim3(DM / BN, MTOT / BM), 256, 0, stream>>>(Ctx, Wob, (float*)d_out);
}